// Round 1
// baseline (99.799 us; speedup 1.0000x reference)
//
#include <hip/hip_runtime.h>
#include <math.h>

// CapLayer on MI355X.
// Key algebraic fact: with b initialized to zero, softmax over the out-caps
// axis of a tensor that is CONSTANT along that axis returns exactly 1/NUM_OUT.
// Iter 1: c = 1/64 -> s[b,o,:] = colsum(pred[b])/64 (o-independent) -> v1
// o-independent -> delta_b o-independent -> b stays o-constant -> all 3
// iterations yield the same v. Output = broadcast(squash(colsum(pred)/64)).
// colsum(pred)[b,d] = sum_s sum_i W[s,d,i] * U[b,s,i],
// U[b,s,i] = sum_p x_flat[b, s*8192 + p*32 + i]  (row-major reinterpret).

#define NSH     32
#define IN_DIM_ 32
#define OUT_DIM_ 64
#define BS_     64
// per-(b,s) contiguous chunk of x: 256 * 32 floats = 8192

__global__ __launch_bounds__(256) void k_reduce(const float* __restrict__ x,
                                                float* __restrict__ U) {
    const int blk = blockIdx.x;                 // b*32 + s  (0..2047)
    const float* xb = x + (size_t)blk * 8192;   // contiguous 32KB chunk
    const int t  = threadIdx.x;
    const int i4 = t & 7;                       // which float4 of the 32-float row
    const int pl = t >> 3;                      // p-lane 0..31

    float4 a = make_float4(0.f, 0.f, 0.f, 0.f);
#pragma unroll
    for (int k = 0; k < 8; ++k) {
        const float4 v = *reinterpret_cast<const float4*>(
            xb + (size_t)(pl + 32 * k) * IN_DIM_ + i4 * 4);
        a.x += v.x; a.y += v.y; a.z += v.z; a.w += v.w;
    }

    __shared__ float4 red[256];
    red[t] = a;
    __syncthreads();
#pragma unroll
    for (int st = 128; st >= 8; st >>= 1) {
        if (t < st) {
            const float4 o = red[t + st];
            red[t].x += o.x; red[t].y += o.y; red[t].z += o.z; red[t].w += o.w;
        }
        __syncthreads();
    }
    if (t < 8) {
        *reinterpret_cast<float4*>(U + (size_t)blk * IN_DIM_ + t * 4) = red[t];
    }
}

__global__ __launch_bounds__(256) void k_finish(const float* __restrict__ U,
                                                const float* __restrict__ W,
                                                float* __restrict__ out) {
    const int b = blockIdx.x;
    const int t = threadIdx.x;

    __shared__ float Ub[NSH * IN_DIM_];         // 1024 floats
#pragma unroll
    for (int q = 0; q < 4; ++q) Ub[t + 256 * q] = U[(size_t)b * 1024 + t + 256 * q];
    __syncthreads();

    const int d  = t & 63;                      // output dim
    const int sg = t >> 6;                      // shared-group chunk 0..3

    float acc = 0.f;
#pragma unroll
    for (int ss = 0; ss < 8; ++ss) {
        const int s = sg * 8 + ss;
        const float4* W4 = reinterpret_cast<const float4*>(
            W + (size_t)s * OUT_DIM_ * IN_DIM_ + (size_t)d * IN_DIM_);
        const float4* U4 = reinterpret_cast<const float4*>(Ub + s * IN_DIM_);
#pragma unroll
        for (int q = 0; q < 8; ++q) {
            const float4 w = W4[q];
            const float4 u = U4[q];
            acc += w.x * u.x + w.y * u.y + w.z * u.z + w.w * u.w;
        }
    }

    __shared__ float red[256];
    red[t] = acc;
    __syncthreads();

    __shared__ float vsh[OUT_DIM_];
    if (t < 64) {
        const float s1 = (red[t] + red[t + 64] + red[t + 128] + red[t + 192])
                         * (1.0f / 64.0f);
        float sq = s1 * s1;
#pragma unroll
        for (int off = 32; off >= 1; off >>= 1) sq += __shfl_xor(sq, off, 64);
        const float norm  = sqrtf(sq);
        const float coeff = norm / (1.0f + sq);   // == n^2/(1+n^2)/n
        vsh[t] = s1 * coeff;
    }
    __syncthreads();

    float* ob = out + (size_t)b * (OUT_DIM_ * OUT_DIM_);
    const float val = vsh[t & 63];
#pragma unroll
    for (int q = 0; q < 16; ++q) ob[t + 256 * q] = val;
}

extern "C" void kernel_launch(void* const* d_in, const int* in_sizes, int n_in,
                              void* d_out, int out_size, void* d_ws, size_t ws_size,
                              hipStream_t stream) {
    const float* x = (const float*)d_in[0];   // [64, 1024, 16, 16] fp32
    const float* W = (const float*)d_in[1];   // [32, 64, 32] fp32
    float* out = (float*)d_out;               // [64, 64, 64] fp32
    float* U   = (float*)d_ws;                // [64, 32, 32] = 256KB scratch

    k_reduce<<<BS_ * NSH, 256, 0, stream>>>(x, U);
    k_finish<<<BS_, 256, 0, stream>>>(U, W, out);
}